// Round 7
// baseline (420.658 us; speedup 1.0000x reference)
//
#include <hip/hip_runtime.h>

typedef __bf16 bf16x8 __attribute__((ext_vector_type(8)));
typedef __bf16 bf16x4 __attribute__((ext_vector_type(4)));
typedef float f32x4 __attribute__((ext_vector_type(4)));

typedef const __attribute__((address_space(1))) void* gas_t;
typedef __attribute__((address_space(3))) void* las_t;

static constexpr int DIM = 2048;
static constexpr size_t MAT = (size_t)DIM * DIM;  // 4194304 elements

__device__ __forceinline__ float sigmoidf_(float x) { return 1.f / (1.f + __expf(-x)); }

// ---------------------------------------------------------------------------
// fp32 -> bf16 conversion for X, Wq, Wk, Wv, Wo  (grid: (4096, 5), 256 thr)
// ---------------------------------------------------------------------------
__global__ void cvt_kernel(const float* __restrict__ x, const float* __restrict__ wq,
                           const float* __restrict__ wk, const float* __restrict__ wv,
                           const float* __restrict__ wo, __bf16* __restrict__ dst) {
  const float* s;
  switch (blockIdx.y) {
    case 0: s = x; break;
    case 1: s = wq; break;
    case 2: s = wk; break;
    case 3: s = wv; break;
    default: s = wo; break;
  }
  __bf16* d = dst + (size_t)blockIdx.y * MAT;
  size_t i = ((size_t)blockIdx.x * 256 + threadIdx.x) * 4;
  float4 v = *(const float4*)(s + i);
  bf16x4 ov;
  ov[0] = (__bf16)v.x; ov[1] = (__bf16)v.y; ov[2] = (__bf16)v.z; ov[3] = (__bf16)v.w;
  *(bf16x4*)(d + i) = ov;
}

// ---------------------------------------------------------------------------
// 128x128 bf16 GEMM, 512 threads = 2 K-groups x 4 waves (IN-BLOCK SPLIT-K).
// Each group stages its own 16 KiB A/B buffers and runs half the K range;
// halves merge in fp32 through a 32 KiB LDS overlay in the epilogue.
// Per-wave work identical to the proven BK=32 kernel; waves/CU 12 -> 16.
// MODE 0: bf16 store.  MODE 1: fp32 store (bias may be nullptr).
// ---------------------------------------------------------------------------
template <int MODE>
__device__ __forceinline__ void gemm512(const __bf16* __restrict__ A, const __bf16* __restrict__ B,
                                        const float* __restrict__ bias, bool bias_row, float scale,
                                        void* __restrict__ Cout, int mtile, int ntile,
                                        int kbeg, int kend, char* smem) {
  const int t = threadIdx.x, lane = t & 63;
  const int w8 = t >> 6, g = w8 >> 2, w = w8 & 3;  // K-group, wave-in-group
  const int l16 = lane & 15, lhi = lane >> 4;
  const int wrow = (w >> 1) * 64, wcol = (w & 1) * 64;
  const int rbase = mtile * 128, cbase = ntile * 128;
  __bf16* Asm = (__bf16*)(smem + g * 16384);
  __bf16* Bsm = (__bf16*)(smem + g * 16384 + 8192);
  const int half = (kend - kbeg) >> 1;  // multiple of 32 by construction
  const int kb = kbeg + g * half, ke = kb + half;
  f32x4 acc[4][4] = {};

  for (int k0 = kb; k0 < ke; k0 += 32) {
    __syncthreads();  // both groups' previous LDS reads complete
#pragma unroll
    for (int i = 0; i < 2; ++i) {
      const int rb = i * 4 + w;          // rowblock 0..7
      const int row = rb * 16 + l16;     // tile row
      const int kk = lhi * 8;            // k-offset in 32-wide slice
      __builtin_amdgcn_global_load_lds((gas_t)(A + (size_t)(rbase + row) * DIM + k0 + kk),
                                       (las_t)(Asm + rb * 512 + lane * 8), 16, 0, 0);
      __builtin_amdgcn_global_load_lds((gas_t)(B + (size_t)(cbase + row) * DIM + k0 + kk),
                                       (las_t)(Bsm + rb * 512 + lane * 8), 16, 0, 0);
    }
    __syncthreads();  // staging visible

    bf16x8 af[4], bf[4];
#pragma unroll
    for (int i = 0; i < 4; ++i)
      af[i] = *(const bf16x8*)(Asm + ((w >> 1) * 4 + i) * 512 + lane * 8);
#pragma unroll
    for (int j = 0; j < 4; ++j)
      bf[j] = *(const bf16x8*)(Bsm + ((w & 1) * 4 + j) * 512 + lane * 8);
#pragma unroll
    for (int i = 0; i < 4; ++i)
#pragma unroll
      for (int j = 0; j < 4; ++j)
        acc[i][j] = __builtin_amdgcn_mfma_f32_16x16x32_bf16(af[i], bf[j], acc[i][j], 0, 0, 0);
  }

  // merge g1's acc into g0's via 32 KiB LDS overlay (2 chunks of 2 i-blocks)
  __syncthreads();  // all main-loop LDS reads done
  float* mbuf = (float*)smem;
#pragma unroll
  for (int ih = 0; ih < 2; ++ih) {
    if (g == 1) {
#pragma unroll
      for (int i2 = 0; i2 < 2; ++i2)
#pragma unroll
        for (int j = 0; j < 4; ++j)
#pragma unroll
          for (int r = 0; r < 4; ++r)
            mbuf[(((w * 2 + i2) * 4 + j) * 4 + r) * 64 + lane] = acc[ih * 2 + i2][j][r];
    }
    __syncthreads();
    if (g == 0) {
#pragma unroll
      for (int i2 = 0; i2 < 2; ++i2)
#pragma unroll
        for (int j = 0; j < 4; ++j)
#pragma unroll
          for (int r = 0; r < 4; ++r)
            acc[ih * 2 + i2][j][r] += mbuf[(((w * 2 + i2) * 4 + j) * 4 + r) * 64 + lane];
    }
    __syncthreads();
  }

  if (g == 0) {
    // epilogue: C/D layout col = lane&15, row = (lane>>4)*4 + r
#pragma unroll
    for (int i = 0; i < 4; ++i)
#pragma unroll
      for (int j = 0; j < 4; ++j)
#pragma unroll
        for (int r = 0; r < 4; ++r) {
          const int row = rbase + wrow + i * 16 + lhi * 4 + r;
          const int col = cbase + wcol + j * 16 + l16;
          float v = acc[i][j][r];
          if (bias) v += bias_row ? bias[row] : bias[col];
          v *= scale;
          if (MODE == 1)
            ((float*)Cout)[(size_t)row * DIM + col] = v;
          else
            ((__bf16*)Cout)[(size_t)row * DIM + col] = (__bf16)v;
        }
  }
}

// ---------------------------------------------------------------------------
// Fused QKV projections. grid (48,16) x 512 thr: sel = x>>4 picks Q / K / V^T.
// ---------------------------------------------------------------------------
__global__ __launch_bounds__(512, 2) void qkv_kernel(
    const __bf16* __restrict__ Xb, const __bf16* __restrict__ Wqb, const __bf16* __restrict__ Wkb,
    const __bf16* __restrict__ Wvb, const float* __restrict__ bq, const float* __restrict__ bk,
    const float* __restrict__ bv, const float* __restrict__ jgate, __bf16* __restrict__ Qo,
    __bf16* __restrict__ Ko, __bf16* __restrict__ Vto) {
  __shared__ __align__(16) char smem[32768];
  const int sel = blockIdx.x >> 4, nt = blockIdx.x & 15, mt = blockIdx.y;
  const __bf16 *A, *B;
  const float* bias;
  __bf16* C;
  bool brow = false;
  float sc = 1.f;
  if (sel == 0) {
    A = Xb; B = Wqb; bias = bq; C = Qo;
    sc = (1.f - 0.1f * sigmoidf_(jgate[0])) * 0.08838834764831843f;  // 1/sqrt(128)
  } else if (sel == 1) {
    A = Xb; B = Wkb; bias = bk; C = Ko;
  } else {
    A = Wvb; B = Xb; bias = bv; C = Vto; brow = true;
  }
  gemm512<0>(A, B, bias, brow, sc, C, mt, nt, 0, DIM, smem);
}

// ---------------------------------------------------------------------------
// Output projection: grid (16,16,2) x 512 thr. z does K in [z*1024, z*1024+1024)
// (in-block split halves it again -> effective split-K x4). z=0 -> d_out with
// bias; z=1 -> fp32 partial P1. reduce_kernel sums.
// ---------------------------------------------------------------------------
__global__ __launch_bounds__(512, 2) void outproj_kernel(const __bf16* __restrict__ Ab,
                                                         const __bf16* __restrict__ Wob,
                                                         const float* __restrict__ bo,
                                                         float* __restrict__ Cout,
                                                         float* __restrict__ P1) {
  __shared__ __align__(16) char smem[32768];
  const int z = blockIdx.z;
  gemm512<1>(Ab, Wob, z == 0 ? bo : nullptr, false, 1.f, z == 0 ? Cout : P1,
             blockIdx.y, blockIdx.x, z * 1024, z * 1024 + 1024, smem);
}

// out += P1  (grid 4096, 256 thr, float4)
__global__ void reduce_kernel(float* __restrict__ out, const float* __restrict__ P1) {
  size_t i = ((size_t)blockIdx.x * 256 + threadIdx.x) * 4;
  float4 a = *(const float4*)(out + i);
  float4 b = *(const float4*)(P1 + i);
  a.x += b.x; a.y += b.y; a.z += b.z; a.w += b.w;
  *(float4*)(out + i) = a;
}

// ---------------------------------------------------------------------------
// Flash attention, KEY-SPLIT waves + KEY-SPLIT grid (z).
// grid (32 qtiles, 16 heads, 2 kranges) = 1024 blocks, 256 thr = 4 waves.
// z-block handles keys [z*1024, z*1024+1024) (16 iters) and writes UNNORMALIZED
// fp32 o-partials + row-sums l; amerge_kernel combines (exact: fixed-max).
// Wave w: qg = w&1 -> 32 q rows, kg = w>>1 -> 32-key half of the 64-key tile.
// LDS: K 16K + V 16K + P 10K = 42 KiB.
// ---------------------------------------------------------------------------
__global__ __launch_bounds__(256, 2) void attn_kernel(const __bf16* __restrict__ Q,
                                                      const __bf16* __restrict__ Kg,
                                                      const __bf16* __restrict__ VT,
                                                      const float* __restrict__ ogate,
                                                      float* __restrict__ O0, float* __restrict__ O1,
                                                      float* __restrict__ l0, float* __restrict__ l1) {
  __shared__ __align__(16) char smem[43008];
  __bf16* Ks = (__bf16*)smem;            // 16 KiB: rb = kg*8 + c*2 + j
  __bf16* Vs = (__bf16*)(smem + 16384);  // 16 KiB: rb = kg*8 + d
  __bf16* Ps = (__bf16*)(smem + 32768);  // 10 KiB: per-wave 32q x 32k, stride 40
  const int t = threadIdx.x, lane = t & 63, w = t >> 6;  // w in 0..3
  const int l16 = lane & 15, lhi = lane >> 4;
  const int qg = w & 1, kg = w >> 1;
  const int h = blockIdx.y, qt = blockIdx.x;  // qt 0..31 (64 q rows each)
  const int z = blockIdx.z;
  float* Op = z ? O1 : O0;
  float* lp = z ? l1 : l0;
  const float beta = sigmoidf_(ogate[0]) * 0.05f / 2048.0f;

  // Q fragments: 2 rowblocks x 4 k-chunks, in registers all kernel
  bf16x8 qf[2][4];
#pragma unroll
  for (int rb = 0; rb < 2; ++rb)
#pragma unroll
    for (int c = 0; c < 4; ++c)
      qf[rb][c] = *(const bf16x8*)(Q + (size_t)(qt * 64 + qg * 32 + rb * 16 + l16) * DIM +
                                   h * 128 + c * 32 + lhi * 8);

  f32x4 oacc[2][8] = {};
  float l_r[2][4] = {};
  __bf16* pw = Ps + w * 1280;

  for (int kt = z * 1024; kt < z * 1024 + 1024; kt += 64) {
    __syncthreads();  // all waves done reading previous Ks/Vs
#pragma unroll
    for (int i = 0; i < 4; ++i) {
      const int rb = i * 4 + w;  // 0..15
      {
        const int kgs = rb >> 3, c = (rb & 7) >> 1, j = rb & 1;
        __builtin_amdgcn_global_load_lds(
            (gas_t)(Kg + (size_t)(kt + kgs * 32 + j * 16 + l16) * DIM + h * 128 + c * 32 + lhi * 8),
            (las_t)(Ks + rb * 512 + lane * 8), 16, 0, 0);
      }
      {
        const int kgs = rb >> 3, d = rb & 7;
        __builtin_amdgcn_global_load_lds(
            (gas_t)(VT + (size_t)(h * 128 + d * 16 + l16) * DIM + kt + kgs * 32 + lhi * 8),
            (las_t)(Vs + rb * 512 + lane * 8), 16, 0, 0);
      }
    }
    __syncthreads();  // staging visible

    // QK^T over this wave's 32-key half; each kf feeds 2 MFMAs
    f32x4 s[2][2];
#pragma unroll
    for (int j = 0; j < 2; ++j) {
      f32x4 a0 = {}, a1 = {};
#pragma unroll
      for (int c = 0; c < 4; ++c) {
        bf16x8 kf = *(const bf16x8*)(Ks + (kg * 8 + c * 2 + j) * 512 + lane * 8);
        a0 = __builtin_amdgcn_mfma_f32_16x16x32_bf16(qf[0][c], kf, a0, 0, 0, 0);
        a1 = __builtin_amdgcn_mfma_f32_16x16x32_bf16(qf[1][c], kf, a1, 0, 0, 0);
      }
      s[0][j] = a0;
      s[1][j] = a1;
    }

    // fixed-max softmax: p = exp(s + beta*key_pos); accumulate row sums
#pragma unroll
    for (int j = 0; j < 2; ++j) {
      const float pb = beta * (float)(kt + kg * 32 + j * 16 + l16);
#pragma unroll
      for (int rb = 0; rb < 2; ++rb)
#pragma unroll
        for (int r = 0; r < 4; ++r) s[rb][j][r] = __expf(s[rb][j][r] + pb);
    }
    float rs[2][4];
#pragma unroll
    for (int rb = 0; rb < 2; ++rb)
#pragma unroll
      for (int r = 0; r < 4; ++r) rs[rb][r] = s[rb][0][r] + s[rb][1][r];
#pragma unroll
    for (int msk = 1; msk < 16; msk <<= 1)
#pragma unroll
      for (int rb = 0; rb < 2; ++rb)
#pragma unroll
        for (int r = 0; r < 4; ++r) rs[rb][r] += __shfl_xor(rs[rb][r], msk, 64);
#pragma unroll
    for (int rb = 0; rb < 2; ++rb)
#pragma unroll
      for (int r = 0; r < 4; ++r) l_r[rb][r] += rs[rb][r];

    // write P (C-layout -> row-major [32 q][32 key], stride 40); per-wave LDS
#pragma unroll
    for (int rb = 0; rb < 2; ++rb)
#pragma unroll
      for (int j = 0; j < 2; ++j)
#pragma unroll
        for (int r = 0; r < 4; ++r)
          pw[(rb * 16 + lhi * 4 + r) * 40 + j * 16 + l16] = (__bf16)s[rb][j][r];

    // PV over the 32-key half; same-wave DS ordering, no barrier needed.
    bf16x8 pa0 = *(const bf16x8*)(pw + (0 * 16 + l16) * 40 + lhi * 8);
    bf16x8 pa1 = *(const bf16x8*)(pw + (1 * 16 + l16) * 40 + lhi * 8);
#pragma unroll
    for (int d = 0; d < 8; ++d) {
      bf16x8 vf = *(const bf16x8*)(Vs + (kg * 8 + d) * 512 + lane * 8);
      oacc[0][d] = __builtin_amdgcn_mfma_f32_16x16x32_bf16(pa0, vf, oacc[0][d], 0, 0, 0);
      oacc[1][d] = __builtin_amdgcn_mfma_f32_16x16x32_bf16(pa1, vf, oacc[1][d], 0, 0, 0);
    }
  }

  // merge the two kg-halves via LDS overlay, then write fp32 partials
  __syncthreads();
  float* mrg = (float*)smem;             // [2 qg][32 row][128 col] fp32 = 32 KiB
  float* lmrg = (float*)(smem + 32768);  // [2 qg][32 row]
  if (kg == 1) {
#pragma unroll
    for (int rb = 0; rb < 2; ++rb)
#pragma unroll
      for (int d = 0; d < 8; ++d)
#pragma unroll
        for (int r = 0; r < 4; ++r)
          mrg[qg * 4096 + (rb * 16 + lhi * 4 + r) * 128 + d * 16 + l16] = oacc[rb][d][r];
    if (l16 == 0)
#pragma unroll
      for (int rb = 0; rb < 2; ++rb)
#pragma unroll
        for (int r = 0; r < 4; ++r) lmrg[qg * 32 + rb * 16 + lhi * 4 + r] = l_r[rb][r];
  }
  __syncthreads();
  if (kg == 0) {
#pragma unroll
    for (int rb = 0; rb < 2; ++rb) {
      float lt[4];
#pragma unroll
      for (int r = 0; r < 4; ++r)
        lt[r] = l_r[rb][r] + lmrg[qg * 32 + rb * 16 + lhi * 4 + r];
      if (l16 == 0)
#pragma unroll
        for (int r = 0; r < 4; ++r)
          lp[(size_t)(qt * 64 + qg * 32 + rb * 16 + lhi * 4 + r) * 16 + h] = lt[r];
#pragma unroll
      for (int d = 0; d < 8; ++d)
#pragma unroll
        for (int r = 0; r < 4; ++r) {
          const int row = qt * 64 + qg * 32 + rb * 16 + lhi * 4 + r;
          const int col = h * 128 + d * 16 + l16;
          Op[(size_t)row * DIM + col] =
              oacc[rb][d][r] + mrg[qg * 4096 + (rb * 16 + lhi * 4 + r) * 128 + d * 16 + l16];
        }
    }
  }
}

// Ab = bf16((O0+O1) / (l0+l1))  (grid 4096, 256 thr, 4 cols/thread)
__global__ void amerge_kernel(const float* __restrict__ O0, const float* __restrict__ O1,
                              const float* __restrict__ l0, const float* __restrict__ l1,
                              __bf16* __restrict__ Ab) {
  size_t i = ((size_t)blockIdx.x * 256 + threadIdx.x) * 4;
  const int row = (int)(i >> 11);
  const int h = (int)(i & 2047) >> 7;
  const float linv = 1.f / (l0[row * 16 + h] + l1[row * 16 + h]);
  float4 a = *(const float4*)(O0 + i);
  float4 b = *(const float4*)(O1 + i);
  bf16x4 o;
  o[0] = (__bf16)((a.x + b.x) * linv);
  o[1] = (__bf16)((a.y + b.y) * linv);
  o[2] = (__bf16)((a.z + b.z) * linv);
  o[3] = (__bf16)((a.w + b.w) * linv);
  *(bf16x4*)(Ab + i) = o;
}

// ---------------------------------------------------------------------------
extern "C" void kernel_launch(void* const* d_in, const int* in_sizes, int n_in,
                              void* d_out, int out_size, void* d_ws, size_t ws_size,
                              hipStream_t stream) {
  const float* X  = (const float*)d_in[0];
  const float* Wq = (const float*)d_in[1];
  const float* bq = (const float*)d_in[2];
  const float* Wk = (const float*)d_in[3];
  const float* bk = (const float*)d_in[4];
  const float* Wv = (const float*)d_in[5];
  const float* bv = (const float*)d_in[6];
  const float* Wo = (const float*)d_in[7];
  const float* bo = (const float*)d_in[8];
  // gates: truth(9), balance(10), order(11), justice(12), harmony(13)
  const float* order_g   = (const float*)d_in[11];
  const float* justice_g = (const float*)d_in[12];

  __bf16* wsb = (__bf16*)d_ws;
  __bf16* Xb  = wsb + 0 * MAT;  // dead after qkv
  __bf16* Wqb = wsb + 1 * MAT;  // dead after qkv
  __bf16* Wkb = wsb + 2 * MAT;  // dead after qkv
  __bf16* Wvb = wsb + 3 * MAT;  // dead after qkv
  __bf16* Wob = wsb + 4 * MAT;  // alive until outproj
  __bf16* Qb  = wsb + 5 * MAT;  // dead after attn
  __bf16* Kb  = wsb + 6 * MAT;
  __bf16* VTb = wsb + 7 * MAT;
  // fp32 attn partials overlay dead regions (each = 2 bf16 slots):
  float* O0 = (float*)(wsb + 1 * MAT);  // slots 1-2 (Wqb,Wkb)
  float* O1 = (float*)(wsb + 3 * MAT);  // slot 3 (Wvb) + ... needs 2 slots:
  // O1 uses slots 3 and 0 is NOT contiguous -> use slot 3 + slot 0? they are
  // not adjacent; instead O1 overlays slots 3..4? Wob must survive. So place
  // O1 in high slot 8 region? slot 8 holds l0/l1 (tiny). Layout decision:
  // l0/l1 at start of slot 8, O1 right after (slot 8 is 8 MB = 1 MAT bf16 =
  // 4 MB fp32 -> NOT enough for 16 MB O1. Use slots 3 (8MB) ... O1 needs 16MB.
  // -> O1 = slots 3 + 8 is non-contiguous. Solution: O1 spans slot 8+9?
  // R2 proved 9 slots (72MB); 10 slots = 80MB unproven. Keep it safe:
  // Put O1 over slots 1-2?? occupied by O0. ALTERNATIVE: Ab overlays slot 0
  // (X, dead) and O1 overlays slots 5-6?? Qb/Kb alive during attn. NO.
  // Final safe layout: O0 = slots 1-2; O1 = slot 3 + slot 0 handled by making
  // O1 CONTIGUOUS at slots 0..1?? conflicts O0.
  // => Simplest correct: O1 lives in slots 0+... not contiguous. So instead
  // shift: O0 = slots 0-1 (X,Wq dead), O1 = slots 2-3 (Wk,Wv dead). DONE.
  float* l0 = (float*)(wsb + 8 * MAT);                 // 128 KB
  float* l1 = (float*)((char*)(wsb + 8 * MAT) + 131072);
  float* P1 = (float*)(wsb + 0 * MAT);  // outproj partial, slots 0-1 (post-amerge)
  __bf16* Ab = wsb + 5 * MAT;           // overlays Qb (dead after attn)

  O0 = (float*)(wsb + 0 * MAT);  // slots 0-1: X,Wqb dead after qkv
  O1 = (float*)(wsb + 2 * MAT);  // slots 2-3: Wkb,Wvb dead after qkv
  P1 = (float*)(wsb + 0 * MAT);  // slots 0-1: O0 dead after amerge

  cvt_kernel<<<dim3(4096, 5), 256, 0, stream>>>(X, Wq, Wk, Wv, Wo, wsb);
  qkv_kernel<<<dim3(48, 16), 512, 0, stream>>>(Xb, Wqb, Wkb, Wvb, bq, bk, bv, justice_g,
                                               Qb, Kb, VTb);
  attn_kernel<<<dim3(32, 16, 2), 256, 0, stream>>>(Qb, Kb, VTb, order_g, O0, O1, l0, l1);
  amerge_kernel<<<4096, 256, 0, stream>>>(O0, O1, l0, l1, Ab);
  outproj_kernel<<<dim3(16, 16, 2), 512, 0, stream>>>(Ab, Wob, bo, (float*)d_out, P1);
  reduce_kernel<<<4096, 256, 0, stream>>>((float*)d_out, P1);
}